// Round 2
// baseline (388.976 us; speedup 1.0000x reference)
//
#include <hip/hip_runtime.h>

#define FEAT 256
#define HID 128
#define NKEYS 2

typedef __bf16 bf16x8 __attribute__((ext_vector_type(8)));
typedef float f32x16 __attribute__((ext_vector_type(16)));

union Frag {
    bf16x8 v;
    unsigned u[4];
    uint4 q;
};

// pack two f32 -> two bf16 (round-half-up) in one v_perm
__device__ __forceinline__ unsigned pack_bf16_2(float f0, float f1) {
    unsigned u0 = __float_as_uint(f0) + 0x8000u;
    unsigned u1 = __float_as_uint(f1) + 0x8000u;
    return __builtin_amdgcn_perm(u1, u0, 0x07060302u);
}

// shifted softplus: softplus(x) - ln2
__device__ __forceinline__ float ssp(float x) {
    float sp = __logf(1.0f + __expf(x));
    sp = (x > 15.0f) ? x : sp;
    return sp - 0.69314718056f;
}

// largest m with off[m] <= g  (off[0]=0, off sorted, n_mols+1 entries)
__device__ __forceinline__ int find_mol(const int* off, int n_mols, int g) {
    int lo = 0, hi = n_mols;
    while (hi - lo > 1) {
        int mid = (lo + hi) >> 1;
        if (off[mid] <= g) lo = mid; else hi = mid;
    }
    return lo;
}

// async global -> LDS, 16B per lane; lptr must be wave-uniform (HW adds lane*16)
__device__ __forceinline__ void gload_lds16(const float* g, void* l) {
    __builtin_amdgcn_global_load_lds(
        (const __attribute__((address_space(1))) unsigned int*)g,
        (__attribute__((address_space(3))) unsigned int*)l,
        16, 0, 0);
}

// Block 0: prefix-scan num_atoms (int32, falling back to int64 if the int32
// interpretation doesn't sum to n_atoms) + zero d_out. Scans are parallel
// (tree reduce + Hillis-Steele) -- no serial thread-0 loops.
// Blocks 1..256: pack W1 -> Bp bf16, layout Bp[c][k] (c = key*HID + j).
__global__ void prep_kernel(const void* __restrict__ num_atoms_raw,
                            const float* __restrict__ W1,
                            int n_mols, int n_atoms,
                            int* __restrict__ off,
                            unsigned short* __restrict__ Bp,
                            float* __restrict__ out, int out_n) {
    if (blockIdx.x > 0) {
        int idx = (blockIdx.x - 1) * 256 + threadIdx.x;   // 0..65535
        int c = idx >> 8;
        int k = idx & 255;
        int key = c >> 7, j = c & 127;
        float f = W1[(size_t)key * FEAT * HID + (size_t)k * HID + j];
        unsigned u = __float_as_uint(f);
        unsigned r = (u + 0x7FFFu + ((u >> 16) & 1u)) >> 16;   // RNE to bf16
        Bp[(size_t)c * FEAT + k] = (unsigned short)r;
        return;
    }
    // zero the output (atomically accumulated by gemm_fused)
    for (int i = threadIdx.x; i < out_n; i += 256) out[i] = 0.0f;

    __shared__ long long tsum[256];
    __shared__ int csum[256];
    int tid = threadIdx.x;
    const int* a32 = (const int*)num_atoms_raw;
    const long long* a64 = (const long long*)num_atoms_raw;
    int chunk = (n_mols + 255) >> 8;
    int lo = tid * chunk;
    if (lo > n_mols) lo = n_mols;
    int hi = lo + chunk;
    if (hi > n_mols) hi = n_mols;

    long long s32 = 0;
    for (int i = lo; i < hi; ++i) s32 += (long long)a32[i];
    tsum[tid] = s32;
    __syncthreads();
    #pragma unroll
    for (int d = 128; d > 0; d >>= 1) {
        if (tid < d) tsum[tid] += tsum[tid + d];
        __syncthreads();
    }
    int mode = (tsum[0] == (long long)n_atoms) ? 0 : 1;
    long long s = s32;
    if (mode) {                      // only touch int64 view if int32 failed
        s = 0;
        for (int i = lo; i < hi; ++i) s += a64[i];
    }
    int v = (int)s;
    csum[tid] = v;
    __syncthreads();
    #pragma unroll
    for (int d = 1; d < 256; d <<= 1) {
        int t = (tid >= d) ? csum[tid - d] : 0;
        __syncthreads();
        csum[tid] += t;
        __syncthreads();
    }
    int run = csum[tid] - v;         // exclusive prefix
    for (int i = lo; i < hi; ++i) {
        off[i] = run;
        run += mode ? (int)a64[i] : a32[i];
    }
    if (hi >= n_mols) off[n_mols] = run;
}

// Fused: C = s_i @ B (bf16 MFMA, fp32 acc), +b1, shifted-softplus, .W2, +b2,
// segment-sum into out[key][mol] via atomics.
//
// Block: 256 threads = 4 waves; tile 64 rows x 256 cols; wave = 64x64.
// A (fp32) is DMA'd into LDS via global_load_lds: 4 chunks x 16KB = 64KB, all
// 16 loads issued in the prologue (16KB in flight per wave), then ONE
// __syncthreads (vmcnt(0)-drain is the desired semantic), then 4 chunks of
// barrier-free MFMA compute with in-loop f32->bf16 conversion (VALU co-issues
// with MFMA). LDS layout: unit (row,u) at pos row*16 + (u ^ (row&15)), done by
// pre-swizzling the per-lane GLOBAL address (DMA dest is linear; rule #21).
// Epilogue structures overlay the A tile after a post-loop barrier; off[] is
// carried in registers from the prologue so the mol search runs in LDS.
__global__ __launch_bounds__(256, 2)
void gemm_fused(const float* __restrict__ A,
                const unsigned short* __restrict__ Bp,
                const float* __restrict__ b1,
                const float* __restrict__ W2,
                const float* __restrict__ b2,
                const int* __restrict__ off,
                float* __restrict__ out,
                int n_atoms, int n_mols) {
    __shared__ uint4 ldsA[4096];               // 64KB: 4 chunks x 1024 units
    // epilogue overlay (valid after post-loop __syncthreads):
    int*   offlds = (int*)ldsA;                          // 8KB
    float (*part)[64] = (float(*)[64])((char*)ldsA + 8192);   // 1KB
    float (*molacc)[4] = (float(*)[4])((char*)ldsA + 9216);   // 32B
    int*   mol0sh = (int*)((char*)ldsA + 9248);

    const int tid  = threadIdx.x;
    const int lane = tid & 63;
    const int wid  = tid >> 6;           // wave id = 64-col group
    const int l31  = lane & 31;
    const int half = lane >> 5;          // 0/1
    const int m0   = blockIdx.x * 64;

    // ---- off[] into registers (issued before the DMA; retires first)
    const bool lds_off_ok = (n_mols + 1) <= 2048;
    int4 ov0, ov1;
    if (lds_off_ok) {
        // off region in ws is followed by Bp (128KB): reading 8KB is always safe
        const int4* o4 = (const int4*)off;
        ov0 = o4[tid * 2];
        ov1 = o4[tid * 2 + 1];
    }

    // ---- DMA the whole 64-row A tile (fp32) into LDS, pre-swizzled source
    #pragma unroll
    for (int i = 0; i < 4; ++i) {
        const int p   = i * 256 + wid * 64 + lane;   // unit pos within a chunk
        const int row = p >> 4;
        const int u   = (p & 15) ^ (row & 15);       // inverse-swizzled source
        int gr = m0 + row;
        if (gr > n_atoms - 1) gr = n_atoms - 1;
        const float* g = A + (size_t)gr * FEAT + u * 4;
        #pragma unroll
        for (int c = 0; c < 4; ++c) {
            gload_lds16(g + c * 64, (void*)&ldsA[c * 1024 + i * 256 + wid * 64]);
        }
    }

    // ---- compute-role constants
    const int c0 = wid * 64 + l31;
    const unsigned short* bb0 = Bp + (size_t)c0 * FEAT + half * 8;
    const unsigned short* bb1 = Bp + (size_t)(c0 + 32) * FEAT + half * 8;
    const int s = l31 & 15;              // same for row l31 and l31+32
    const float b1c0 = b1[c0], b1c1 = b1[c0 + 32];
    const float w2c0 = W2[c0], w2c1 = W2[c0 + 32];

    __syncthreads();   // vmcnt(0)+barrier: all DMA'd A data visible to all waves

    f32x16 acc00 = 0.0f, acc01 = 0.0f, acc10 = 0.0f, acc11 = 0.0f;

    #pragma unroll
    for (int c = 0; c < 4; ++c) {
        const uint4* lbuf = ldsA + c * 1024;
        const int kb = c * 64;
        Frag bf0[4], bf1[4];
        #pragma unroll
        for (int j = 0; j < 4; ++j) {
            bf0[j].q = *(const uint4*)(bb0 + kb + j * 16);
            bf1[j].q = *(const uint4*)(bb1 + kb + j * 16);
        }
        #pragma unroll
        for (int j = 0; j < 4; ++j) {
            const int u0 = j * 4 + half * 2;         // even
            const int q0 = u0 ^ s;                   // unit u0
            // row l31 and row l31+32 (same &15 swizzle)
            const int base0 = l31 * 16;
            const int base1 = (l31 + 32) * 16;
            uint4 lo0 = lbuf[base0 + q0];
            uint4 hi0 = lbuf[base0 + (q0 ^ 1)];
            uint4 lo1 = lbuf[base1 + q0];
            uint4 hi1 = lbuf[base1 + (q0 ^ 1)];
            const float4 fl0 = *(const float4*)&lo0;
            const float4 fh0 = *(const float4*)&hi0;
            const float4 fl1 = *(const float4*)&lo1;
            const float4 fh1 = *(const float4*)&hi1;
            Frag a0, a1;
            a0.u[0] = pack_bf16_2(fl0.x, fl0.y);
            a0.u[1] = pack_bf16_2(fl0.z, fl0.w);
            a0.u[2] = pack_bf16_2(fh0.x, fh0.y);
            a0.u[3] = pack_bf16_2(fh0.z, fh0.w);
            a1.u[0] = pack_bf16_2(fl1.x, fl1.y);
            a1.u[1] = pack_bf16_2(fl1.z, fl1.w);
            a1.u[2] = pack_bf16_2(fh1.x, fh1.y);
            a1.u[3] = pack_bf16_2(fh1.z, fh1.w);
            acc00 = __builtin_amdgcn_mfma_f32_32x32x16_bf16(a0.v, bf0[j].v, acc00, 0, 0, 0);
            acc01 = __builtin_amdgcn_mfma_f32_32x32x16_bf16(a0.v, bf1[j].v, acc01, 0, 0, 0);
            acc10 = __builtin_amdgcn_mfma_f32_32x32x16_bf16(a1.v, bf0[j].v, acc10, 0, 0, 0);
            acc11 = __builtin_amdgcn_mfma_f32_32x32x16_bf16(a1.v, bf1[j].v, acc11, 0, 0, 0);
        }
    }

    __syncthreads();   // all ldsA reads done -> overlay region becomes safe

    // ---- spill off[] regs into LDS, zero molacc
    if (lds_off_ok) {
        ((int4*)offlds)[tid * 2]     = ov0;
        ((int4*)offlds)[tid * 2 + 1] = ov1;
    }
    if (tid < NKEYS * 4) molacc[tid >> 2][tid & 3] = 0.0f;

    // ---- epilogue: act + .W2, column-reduce per row, stash in LDS
    #pragma unroll
    for (int rt = 0; rt < 2; ++rt) {
        const f32x16& Ac0 = rt ? acc10 : acc00;
        const f32x16& Ac1 = rt ? acc11 : acc01;
        #pragma unroll
        for (int r = 0; r < 16; ++r) {
            float t = ssp(Ac0[r] + b1c0) * w2c0 + ssp(Ac1[r] + b1c1) * w2c1;
            t += __shfl_xor(t, 1);
            t += __shfl_xor(t, 2);
            t += __shfl_xor(t, 4);
            t += __shfl_xor(t, 8);
            t += __shfl_xor(t, 16);
            if (l31 == r) {
                int row = rt * 32 + (r & 3) + 8 * (r >> 2) + 4 * half;
                part[wid][row] = t;
            }
        }
    }
    __syncthreads();

    if (tid < NKEYS * 64) {
        int key = tid >> 6, r = tid & 63;
        int gm = m0 + r;
        const int* o = lds_off_ok ? offlds : off;
        int mol0 = find_mol(o, n_mols, m0);
        if (tid == 0) *mol0sh = mol0;
        if (gm < n_atoms) {
            int mol = find_mol(o, n_mols, gm);
            float val = part[2 * key][r] + part[2 * key + 1][r] + b2[key];
            int ml = mol - mol0;
            if (ml < 4) atomicAdd(&molacc[key][ml], val);
            else        atomicAdd(&out[(size_t)key * n_mols + mol], val);
        }
    }
    __syncthreads();

    if (tid < NKEYS * 4) {
        int key = tid >> 2, ml = tid & 3;
        int mol = *mol0sh + ml;
        if (mol < n_mols) {
            float v = molacc[key][ml];
            if (v != 0.0f) atomicAdd(&out[(size_t)key * n_mols + mol], v);
        }
    }
}

extern "C" void kernel_launch(void* const* d_in, const int* in_sizes, int n_in,
                              void* d_out, int out_size, void* d_ws, size_t ws_size,
                              hipStream_t stream) {
    const float* s_i      = (const float*)d_in[0];
    // d_in[1] = xyz: unused by the reference output
    const void*  num_atoms = d_in[2];
    const float* W1 = (const float*)d_in[3];
    const float* b1 = (const float*)d_in[4];
    const float* W2 = (const float*)d_in[5];
    const float* b2 = (const float*)d_in[6];
    int n_atoms = in_sizes[0] / FEAT;
    int n_mols  = in_sizes[2];
    float* out = (float*)d_out;

    int* off = (int*)d_ws;
    size_t off_bytes = (((size_t)(n_mols + 1) * 4) + 255) & ~(size_t)255;
    unsigned short* Bp = (unsigned short*)((char*)d_ws + off_bytes);

    int pack_blocks = (NKEYS * HID * FEAT) / 256;   // 256
    prep_kernel<<<1 + pack_blocks, 256, 0, stream>>>(num_atoms, W1, n_mols, n_atoms,
                                                     off, Bp, out, out_size);

    int gblocks = (n_atoms + 63) / 64;
    gemm_fused<<<gblocks, 256, 0, stream>>>(s_i, Bp, b1, W2, b2, off, out, n_atoms, n_mols);
}

// Round 3
// 373.043 us; speedup vs baseline: 1.0427x; 1.0427x over previous
//
#include <hip/hip_runtime.h>

#define FEAT 256
#define HID 128
#define NKEYS 2

typedef __bf16 bf16x8 __attribute__((ext_vector_type(8)));
typedef float f32x16 __attribute__((ext_vector_type(16)));

union Frag {
    bf16x8 v;
    unsigned u[4];
    uint4 q;
};

// pack two f32 -> two bf16 (round-half-up) in one v_perm
__device__ __forceinline__ unsigned pack_bf16_2(float f0, float f1) {
    unsigned u0 = __float_as_uint(f0) + 0x8000u;
    unsigned u1 = __float_as_uint(f1) + 0x8000u;
    return __builtin_amdgcn_perm(u1, u0, 0x07060302u);
}

// shifted softplus: softplus(x) - ln2
__device__ __forceinline__ float ssp(float x) {
    float sp = __logf(1.0f + __expf(x));
    sp = (x > 15.0f) ? x : sp;
    return sp - 0.69314718056f;
}

// largest m with off[m] <= g  (off[0]=0, off sorted, n_mols+1 entries)
__device__ __forceinline__ int find_mol(const int* off, int n_mols, int g) {
    int lo = 0, hi = n_mols;
    while (hi - lo > 1) {
        int mid = (lo + hi) >> 1;
        if (off[mid] <= g) lo = mid; else hi = mid;
    }
    return lo;
}

// async global -> LDS, 16B per lane; lptr must be wave-uniform (HW adds lane*16)
__device__ __forceinline__ void gload_lds16(const float* g, void* l) {
    __builtin_amdgcn_global_load_lds(
        (const __attribute__((address_space(1))) unsigned int*)g,
        (__attribute__((address_space(3))) unsigned int*)l,
        16, 0, 0);
}

// Block 0: prefix-scan num_atoms (int32, falling back to int64 if the int32
// interpretation doesn't sum to n_atoms) + zero d_out (parallel scans).
// Blocks 1..256: pack W1 -> Bp bf16, layout Bp[c][k] (c = key*HID + j).
__global__ void prep_kernel(const void* __restrict__ num_atoms_raw,
                            const float* __restrict__ W1,
                            int n_mols, int n_atoms,
                            int* __restrict__ off,
                            unsigned short* __restrict__ Bp,
                            float* __restrict__ out, int out_n) {
    if (blockIdx.x > 0) {
        int idx = (blockIdx.x - 1) * 256 + threadIdx.x;   // 0..65535
        int c = idx >> 8;
        int k = idx & 255;
        int key = c >> 7, j = c & 127;
        float f = W1[(size_t)key * FEAT * HID + (size_t)k * HID + j];
        unsigned u = __float_as_uint(f);
        unsigned r = (u + 0x7FFFu + ((u >> 16) & 1u)) >> 16;   // RNE to bf16
        Bp[(size_t)c * FEAT + k] = (unsigned short)r;
        return;
    }
    for (int i = threadIdx.x; i < out_n; i += 256) out[i] = 0.0f;

    __shared__ long long tsum[256];
    __shared__ int csum[256];
    int tid = threadIdx.x;
    const int* a32 = (const int*)num_atoms_raw;
    const long long* a64 = (const long long*)num_atoms_raw;
    int chunk = (n_mols + 255) >> 8;
    int lo = tid * chunk;
    if (lo > n_mols) lo = n_mols;
    int hi = lo + chunk;
    if (hi > n_mols) hi = n_mols;

    long long s32 = 0;
    for (int i = lo; i < hi; ++i) s32 += (long long)a32[i];
    tsum[tid] = s32;
    __syncthreads();
    #pragma unroll
    for (int d = 128; d > 0; d >>= 1) {
        if (tid < d) tsum[tid] += tsum[tid + d];
        __syncthreads();
    }
    int mode = (tsum[0] == (long long)n_atoms) ? 0 : 1;
    long long s = s32;
    if (mode) {
        s = 0;
        for (int i = lo; i < hi; ++i) s += a64[i];
    }
    int v = (int)s;
    csum[tid] = v;
    __syncthreads();
    #pragma unroll
    for (int d = 1; d < 256; d <<= 1) {
        int t = (tid >= d) ? csum[tid - d] : 0;
        __syncthreads();
        csum[tid] += t;
        __syncthreads();
    }
    int run = csum[tid] - v;
    for (int i = lo; i < hi; ++i) {
        off[i] = run;
        run += mode ? (int)a64[i] : a32[i];
    }
    if (hi >= n_mols) off[n_mols] = run;
}

// Persistent-block fused GEMM + MLP epilogue + segment-sum.
// 512 threads = 8 waves; wave w owns output cols [w*32, w*32+32) (key = w>>2).
// Tile = 64 rows; K split into 4 chunks of 64. A chunk (64x64 fp32 = 16KB) is
// DMA'd via global_load_lds into a 2-buffer pipeline: B frags for the current
// chunk load FIRST (their vmcnt wait then leaves the newer DMAs in flight),
// then next chunk's DMA is issued, then compute. One __syncthreads per chunk.
// LDS 44.6KB -> 2 blocks/CU; VGPR target <=128 -> 16 waves/CU (50% occ).
__global__ __launch_bounds__(512, 4)
void gemm_fused(const float* __restrict__ A,
                const unsigned short* __restrict__ Bp,
                const float* __restrict__ b1,
                const float* __restrict__ W2,
                const float* __restrict__ b2,
                const int* __restrict__ off,
                float* __restrict__ out,
                int n_atoms, int n_mols, int ntiles, int stride) {
    __shared__ uint4  ldsA[2][1024];      // 2 x 16KB A-chunk (64 rows x 16 units)
    __shared__ int    offlds[2048];       // 8KB prefix offsets
    __shared__ float  part[2][8][64];     // [tile parity][wave][row]
    __shared__ int    rowmol[2][64];
    __shared__ float  molacc[2][NKEYS][4];

    const int tid  = threadIdx.x;
    const int lane = tid & 63;
    const int wid  = tid >> 6;            // 0..7
    const int l31  = lane & 31;
    const int half = lane >> 5;

    // ---- prologue: off[] -> LDS (8KB read is safe: ws pads off region to 8KB)
    const bool lds_ok = (n_mols + 1) <= 2048;
    if (lds_ok) ((int4*)offlds)[tid] = ((const int4*)off)[tid];
    if (tid < 2 * NKEYS * 4) {
        int b = tid >> 3;
        molacc[b][(tid >> 2) & 1][tid & 3] = 0.0f;
    }
    const float b2k0 = b2[0], b2k1 = b2[1];
    const int c0 = wid * 32 + l31;
    const unsigned short* bb = Bp + (size_t)c0 * FEAT + half * 8;
    const float b1c = b1[c0];
    const float w2c = W2[c0];
    const int rB = l31 + 32;
    const int x  = l31 & 15;

    int t = blockIdx.x;
    int cur = 0;

    // stage chunk (tile, c) into ldsA[buf]: per thread 2 DMAs of 16B.
    // LDS unit (row r, u) holds source floats u_src*4.. where
    // u_src = u ^ (r & 15)  (involution; read side applies the same XOR).
    auto stage = [&](int tile, int c, int buf) {
        const int m0s = tile * 64;
        #pragma unroll
        for (int i = 0; i < 2; ++i) {
            const int pos = wid * 128 + i * 64;        // wave-uniform dest unit
            const int r   = (pos >> 4) + (lane >> 4);  // this lane's row
            const int u   = (lane & 15) ^ (r & 15);    // inverse-swizzled src
            int gr = m0s + r;
            if (gr > n_atoms - 1) gr = n_atoms - 1;
            gload_lds16(A + (size_t)gr * FEAT + c * 64 + u * 4,
                        (void*)(&ldsA[buf][pos]));
        }
    };

    stage(t, 0, 0);
    __syncthreads();

    int it = 0;
    for (; t < ntiles; t += stride, ++it) {
        const int tp = it & 1;
        const int m0 = t * 64;
        f32x16 acc0 = 0.0f, acc1 = 0.0f;

        #pragma unroll
        for (int c = 0; c < 4; ++c) {
            // B frags for this chunk FIRST: issued before the DMAs below so the
            // compiler's wait for them is a counted vmcnt that keeps DMA in flight
            Frag bw[4];
            #pragma unroll
            for (int j = 0; j < 4; ++j)
                bw[j].q = *(const uint4*)(bb + c * 64 + j * 16);
            __builtin_amdgcn_sched_barrier(0);

            // issue next chunk's DMA (streams under this chunk's compute)
            const bool last = (c == 3) && (t + stride >= ntiles);
            if (!last) {
                const int nt = (c < 3) ? t : (t + stride);
                stage(nt, (c + 1) & 3, cur ^ 1);
            }

            if (c == 0 && tid < 64) {
                int gm = m0 + tid;
                if (gm > n_atoms - 1) gm = n_atoms - 1;
                rowmol[tp][tid] = lds_ok ? find_mol(offlds, n_mols, gm)
                                         : find_mol(off, n_mols, gm);
            }

            // compute current chunk
            const uint4* lbuf = ldsA[cur];
            #pragma unroll
            for (int ks = 0; ks < 4; ++ks) {
                const int u0 = ks * 4 + half * 2;
                const int us = u0 ^ x;
                uint4 lo0 = lbuf[l31 * 16 + us];
                uint4 hi0 = lbuf[l31 * 16 + (us ^ 1)];
                uint4 lo1 = lbuf[rB  * 16 + us];
                uint4 hi1 = lbuf[rB  * 16 + (us ^ 1)];
                const float4 fl0 = *(const float4*)&lo0;
                const float4 fh0 = *(const float4*)&hi0;
                const float4 fl1 = *(const float4*)&lo1;
                const float4 fh1 = *(const float4*)&hi1;
                Frag a0, a1;
                a0.u[0] = pack_bf16_2(fl0.x, fl0.y);
                a0.u[1] = pack_bf16_2(fl0.z, fl0.w);
                a0.u[2] = pack_bf16_2(fh0.x, fh0.y);
                a0.u[3] = pack_bf16_2(fh0.z, fh0.w);
                a1.u[0] = pack_bf16_2(fl1.x, fl1.y);
                a1.u[1] = pack_bf16_2(fl1.z, fl1.w);
                a1.u[2] = pack_bf16_2(fh1.x, fh1.y);
                a1.u[3] = pack_bf16_2(fh1.z, fh1.w);
                acc0 = __builtin_amdgcn_mfma_f32_32x32x16_bf16(a0.v, bw[ks].v, acc0, 0, 0, 0);
                acc1 = __builtin_amdgcn_mfma_f32_32x32x16_bf16(a1.v, bw[ks].v, acc1, 0, 0, 0);
            }

            if (c == 3) {
                // epilogue: act + .W2, reduce this wave's 32 cols per row
                #pragma unroll
                for (int rt = 0; rt < 2; ++rt) {
                    const f32x16& Ac = rt ? acc1 : acc0;
                    #pragma unroll
                    for (int r = 0; r < 16; ++r) {
                        float v = ssp(Ac[r] + b1c) * w2c;
                        v += __shfl_xor(v, 1);
                        v += __shfl_xor(v, 2);
                        v += __shfl_xor(v, 4);
                        v += __shfl_xor(v, 8);
                        v += __shfl_xor(v, 16);
                        if (l31 == r) {
                            int row = rt * 32 + (r & 3) + 8 * (r >> 2) + 4 * half;
                            part[tp][wid][row] = v;
                        }
                    }
                }
            }

            __syncthreads();
            cur ^= 1;

            if (c == 3) {
                // deferred flush of previous tile's molacc (written pre-barriers)
                if (it > 0 && tid < NKEYS * 4) {
                    const int pp = tp ^ 1;
                    int k = tid >> 2, ml = tid & 3;
                    int mol = rowmol[pp][0] + ml;
                    if (mol < n_mols) {
                        float v = molacc[pp][k][ml];
                        if (v != 0.0f) atomicAdd(&out[(size_t)k * n_mols + mol], v);
                        molacc[pp][k][ml] = 0.0f;
                    }
                }
                // per-row atomics for this tile
                if (tid < NKEYS * 64) {
                    int k = tid >> 6, r = tid & 63;
                    int gm = m0 + r;
                    if (gm < n_atoms) {
                        float val = part[tp][4 * k][r] + part[tp][4 * k + 1][r]
                                  + part[tp][4 * k + 2][r] + part[tp][4 * k + 3][r]
                                  + (k ? b2k1 : b2k0);
                        int mol = rowmol[tp][r];
                        int ml  = mol - rowmol[tp][0];
                        if (ml < 4) atomicAdd(&molacc[tp][k][ml], val);
                        else        atomicAdd(&out[(size_t)k * n_mols + mol], val);
                    }
                }
            }
        }
    }

    // final flush of the last tile's molacc
    __syncthreads();
    const int tpl = (it - 1) & 1;
    if (tid < NKEYS * 4) {
        int k = tid >> 2, ml = tid & 3;
        int mol = rowmol[tpl][0] + ml;
        if (mol < n_mols) {
            float v = molacc[tpl][k][ml];
            if (v != 0.0f) atomicAdd(&out[(size_t)k * n_mols + mol], v);
        }
    }
}

extern "C" void kernel_launch(void* const* d_in, const int* in_sizes, int n_in,
                              void* d_out, int out_size, void* d_ws, size_t ws_size,
                              hipStream_t stream) {
    const float* s_i      = (const float*)d_in[0];
    // d_in[1] = xyz: unused by the reference output
    const void*  num_atoms = d_in[2];
    const float* W1 = (const float*)d_in[3];
    const float* b1 = (const float*)d_in[4];
    const float* W2 = (const float*)d_in[5];
    const float* b2 = (const float*)d_in[6];
    int n_atoms = in_sizes[0] / FEAT;
    int n_mols  = in_sizes[2];
    float* out = (float*)d_out;

    int* off = (int*)d_ws;
    size_t off_bytes = (((size_t)(n_mols + 1) * 4) + 255) & ~(size_t)255;
    if (off_bytes < 8192) off_bytes = 8192;   // gemm_fused reads 8KB of off
    unsigned short* Bp = (unsigned short*)((char*)d_ws + off_bytes);

    int pack_blocks = (NKEYS * HID * FEAT) / 256;   // 256
    prep_kernel<<<1 + pack_blocks, 256, 0, stream>>>(num_atoms, W1, n_mols, n_atoms,
                                                     off, Bp, out, out_size);

    int ntiles  = (n_atoms + 63) / 64;
    int nblocks = ntiles < 512 ? ntiles : 512;
    gemm_fused<<<nblocks, 512, 0, stream>>>(s_i, Bp, b1, W2, b2, off, out,
                                            n_atoms, n_mols, ntiles, nblocks);
}